// Round 1
// baseline (248.159 us; speedup 1.0000x reference)
//
#include <hip/hip_runtime.h>

constexpr int B = 4, C = 128, H = 256, W = 512;
constexpr int HW = H * W;

__global__ __launch_bounds__(256) void warp_flow_kernel(
    const float* __restrict__ x, const float* __restrict__ flow,
    float* __restrict__ out) {
  const int pid = blockIdx.x * blockDim.x + threadIdx.x;  // [0, B*H*W)
  const int w = pid & (W - 1);
  const int h = (pid >> 9) & (H - 1);
  const int b = pid >> 17;

  // flow layout [B,2,H,W]
  const int fidx = ((b * 2) * H + h) * W + w;
  const float flx = flow[fidx];
  const float fly = flow[fidx + HW];

  // Replicate reference arithmetic (normalized grid round-trip, fp32)
  const float gx = (-1.0f + 2.0f * (float)w / (float)(W - 1)) + flx * 2.0f / (float)(W - 1);
  const float gy = (-1.0f + 2.0f * (float)h / (float)(H - 1)) + fly * 2.0f / (float)(H - 1);
  const float fx = (gx + 1.0f) * 0.5f * (float)(W - 1);
  const float fy = (gy + 1.0f) * 0.5f * (float)(H - 1);

  const float x0f = floorf(fx), y0f = floorf(fy);
  const float x1f = x0f + 1.0f, y1f = y0f + 1.0f;
  const float wx1 = fx - x0f, wx0 = 1.0f - wx1;
  const float wy1 = fy - y0f, wy0 = 1.0f - wy1;

  const bool vx0 = (x0f >= 0.0f) && (x0f <= (float)(W - 1));
  const bool vx1 = (x1f >= 0.0f) && (x1f <= (float)(W - 1));
  const bool vy0 = (y0f >= 0.0f) && (y0f <= (float)(H - 1));
  const bool vy1 = (y1f >= 0.0f) && (y1f <= (float)(H - 1));

  float w00 = wx0 * wy0 * ((vx0 && vy0) ? 1.0f : 0.0f);
  float w10 = wx1 * wy0 * ((vx1 && vy0) ? 1.0f : 0.0f);
  float w01 = wx0 * wy1 * ((vx0 && vy1) ? 1.0f : 0.0f);
  float w11 = wx1 * wy1 * ((vx1 && vy1) ? 1.0f : 0.0f);

  const float msum = w00 + w10 + w01 + w11;
  const float mask = (msum >= 0.9999f) ? 1.0f : 0.0f;
  // out * mask  ==  (each weight * mask) applied to vals
  w00 *= mask; w10 *= mask; w01 *= mask; w11 *= mask;

  // clip-then-cast (weights already zero for invalid corners)
  const int ix0 = min(max((int)x0f, 0), W - 1);
  const int ix1 = min(max((int)x1f, 0), W - 1);
  const int iy0 = min(max((int)y0f, 0), H - 1);
  const int iy1 = min(max((int)y1f, 0), H - 1);

  const int p00 = iy0 * W + ix0;
  const int p10 = iy0 * W + ix1;
  const int p01 = iy1 * W + ix0;
  const int p11 = iy1 * W + ix1;

  const float* __restrict__ xp = x + (size_t)b * C * HW;
  float* __restrict__ op = out + (size_t)b * C * HW + h * W + w;

#pragma unroll 4
  for (int c = 0; c < C; ++c) {
    const int coff = c * HW;
    const float v00 = xp[coff + p00];
    const float v10 = xp[coff + p10];
    const float v01 = xp[coff + p01];
    const float v11 = xp[coff + p11];
    op[coff] = w00 * v00 + w10 * v10 + w01 * v01 + w11 * v11;
  }
}

extern "C" void kernel_launch(void* const* d_in, const int* in_sizes, int n_in,
                              void* d_out, int out_size, void* d_ws, size_t ws_size,
                              hipStream_t stream) {
  const float* x = (const float*)d_in[0];
  const float* flow = (const float*)d_in[1];
  float* out = (float*)d_out;
  const int npix = B * H * W;              // 524288
  const int block = 256;
  const int grid = npix / block;           // 2048
  warp_flow_kernel<<<grid, block, 0, stream>>>(x, flow, out);
}

// Round 2
// 207.740 us; speedup vs baseline: 1.1946x; 1.1946x over previous
//
#include <hip/hip_runtime.h>

constexpr int B = 4, C = 128, H = 256, W = 512;
constexpr int HW = H * W;
constexpr int CPB = 64;  // channels per blockIdx.y slice

__global__ __launch_bounds__(256) void warp_flow_kernel(
    const float* __restrict__ x, const float* __restrict__ flow,
    float* __restrict__ out) {
  // XCD-aware swizzle: 2048 x-blocks, 8 XCDs, round-robin dispatch.
  // swz gives XCD k the contiguous block range [k*256,(k+1)*256) =
  // 128 contiguous image rows -> each x row fetched by exactly one XCD L2.
  const int orig = blockIdx.x;
  const int swz = ((orig & 7) << 8) | (orig >> 3);  // bijective on [0,2048)

  const int pid = swz * 256 + threadIdx.x;  // [0, B*H*W)
  const int w = pid & (W - 1);
  const int h = (pid >> 9) & (H - 1);
  const int b = pid >> 17;

  // flow layout [B,2,H,W]
  const int fidx = ((b * 2) * H + h) * W + w;
  const float flx = flow[fidx];
  const float fly = flow[fidx + HW];

  // Replicate reference arithmetic (normalized grid round-trip, fp32)
  const float gx = (-1.0f + 2.0f * (float)w / (float)(W - 1)) + flx * 2.0f / (float)(W - 1);
  const float gy = (-1.0f + 2.0f * (float)h / (float)(H - 1)) + fly * 2.0f / (float)(H - 1);
  const float fx = (gx + 1.0f) * 0.5f * (float)(W - 1);
  const float fy = (gy + 1.0f) * 0.5f * (float)(H - 1);

  const float x0f = floorf(fx), y0f = floorf(fy);
  const float x1f = x0f + 1.0f, y1f = y0f + 1.0f;
  const float wx1 = fx - x0f, wx0 = 1.0f - wx1;
  const float wy1 = fy - y0f, wy0 = 1.0f - wy1;

  const bool vx0 = (x0f >= 0.0f) && (x0f <= (float)(W - 1));
  const bool vx1 = (x1f >= 0.0f) && (x1f <= (float)(W - 1));
  const bool vy0 = (y0f >= 0.0f) && (y0f <= (float)(H - 1));
  const bool vy1 = (y1f >= 0.0f) && (y1f <= (float)(H - 1));

  float w00 = wx0 * wy0 * ((vx0 && vy0) ? 1.0f : 0.0f);
  float w10 = wx1 * wy0 * ((vx1 && vy0) ? 1.0f : 0.0f);
  float w01 = wx0 * wy1 * ((vx0 && vy1) ? 1.0f : 0.0f);
  float w11 = wx1 * wy1 * ((vx1 && vy1) ? 1.0f : 0.0f);

  const float msum = w00 + w10 + w01 + w11;
  const float mask = (msum >= 0.9999f) ? 1.0f : 0.0f;
  w00 *= mask; w10 *= mask; w01 *= mask; w11 *= mask;

  const int ix0 = min(max((int)x0f, 0), W - 1);
  const int ix1 = min(max((int)x1f, 0), W - 1);
  const int iy0 = min(max((int)y0f, 0), H - 1);
  const int iy1 = min(max((int)y1f, 0), H - 1);

  const int p00 = iy0 * W + ix0;
  const int p10 = iy0 * W + ix1;
  const int p01 = iy1 * W + ix0;
  const int p11 = iy1 * W + ix1;

  const int c0 = blockIdx.y * CPB;
  const float* __restrict__ xp = x + ((size_t)b * C + c0) * HW;
  float* __restrict__ op = out + ((size_t)b * C + c0) * HW + h * W + w;

#pragma unroll 8
  for (int c = 0; c < CPB; ++c) {
    const int coff = c * HW;
    const float v00 = xp[coff + p00];
    const float v10 = xp[coff + p10];
    const float v01 = xp[coff + p01];
    const float v11 = xp[coff + p11];
    const float r = w00 * v00 + w10 * v10 + w01 * v01 + w11 * v11;
    __builtin_nontemporal_store(r, &op[coff]);
  }
}

extern "C" void kernel_launch(void* const* d_in, const int* in_sizes, int n_in,
                              void* d_out, int out_size, void* d_ws, size_t ws_size,
                              hipStream_t stream) {
  const float* x = (const float*)d_in[0];
  const float* flow = (const float*)d_in[1];
  float* out = (float*)d_out;
  const int npix = B * H * W;                 // 524288
  dim3 grid(npix / 256, C / CPB);             // (2048, 2)
  warp_flow_kernel<<<grid, dim3(256), 0, stream>>>(x, flow, out);
}

// Round 3
// 201.560 us; speedup vs baseline: 1.2312x; 1.0307x over previous
//
#include <hip/hip_runtime.h>

constexpr int B = 4, C = 128, H = 256, W = 512;
constexpr int HW = H * W;

constexpr int TW = 64, TH = 16;        // tile of pixels per block
constexpr int HALO = 8;                // covers |flow| <= 8 px; else fallback
constexpr int SH = TH + 2 * HALO + 2;  // 34 staged rows  [r0-8 .. r0+TH+9]
constexpr int SW = TW + 2 * HALO + 2;  // 82 staged cols  [c0-8 .. c0+TW+9]
constexpr int SN = SH * SW;            // 2788 floats = 11.2 KB
constexpr int CPG = 32;                // channels per block (grid.y = 4)

__global__ __launch_bounds__(256) void warp_flow_kernel(
    const float* __restrict__ x, const float* __restrict__ flow,
    float* __restrict__ out) {
  __shared__ float sm[SN];

  // XCD-contiguous swizzle over 512 tiles: XCD k owns tiles [64k,64k+64)
  // (8 tile-rows of one image half) -> halo rows shared within one L2.
  const int orig = blockIdx.x;
  const int swz = ((orig & 7) << 6) | (orig >> 3);  // bijective on [0,512)

  const int b = swz >> 7;            // 128 tiles per image
  const int tid = swz & 127;
  const int r0 = (tid >> 3) * TH;    // tile row origin
  const int c0 = (tid & 7) * TW;     // tile col origin
  const int cg0 = blockIdx.y * CPG;  // channel group start

  const int t = threadIdx.x;
  const int lw = t & 63;        // pixel col within tile (wave = one row)
  const int lr = t >> 6;        // base row within tile (0..3)

  // ---- per-pixel precompute (4 px/thread, rows lr + 4k) ----
  float w00[4], w10[4], w01[4], w11[4];
  int o00[4], o10[4], o01[4], o11[4];  // LDS elem offs (in-tile) or plane offs (fallback)
  int pout[4];
  unsigned fb = 0;  // fallback bitmask

#pragma unroll
  for (int k = 0; k < 4; ++k) {
    const int h = r0 + lr + 4 * k;
    const int w = c0 + lw;

    const int fidx = ((b * 2) * H + h) * W + w;
    const float flx = flow[fidx];
    const float fly = flow[fidx + HW];

    // replicate reference arithmetic (fp32, align_corners=True round trip)
    const float gx = (-1.0f + 2.0f * (float)w / (float)(W - 1)) + flx * 2.0f / (float)(W - 1);
    const float gy = (-1.0f + 2.0f * (float)h / (float)(H - 1)) + fly * 2.0f / (float)(H - 1);
    const float fx = (gx + 1.0f) * 0.5f * (float)(W - 1);
    const float fy = (gy + 1.0f) * 0.5f * (float)(H - 1);

    const float x0f = floorf(fx), y0f = floorf(fy);
    const float x1f = x0f + 1.0f, y1f = y0f + 1.0f;
    const float wx1 = fx - x0f, wx0 = 1.0f - wx1;
    const float wy1 = fy - y0f, wy0 = 1.0f - wy1;

    const bool vx0 = (x0f >= 0.0f) && (x0f <= (float)(W - 1));
    const bool vx1 = (x1f >= 0.0f) && (x1f <= (float)(W - 1));
    const bool vy0 = (y0f >= 0.0f) && (y0f <= (float)(H - 1));
    const bool vy1 = (y1f >= 0.0f) && (y1f <= (float)(H - 1));

    float a00 = wx0 * wy0 * ((vx0 && vy0) ? 1.0f : 0.0f);
    float a10 = wx1 * wy0 * ((vx1 && vy0) ? 1.0f : 0.0f);
    float a01 = wx0 * wy1 * ((vx0 && vy1) ? 1.0f : 0.0f);
    float a11 = wx1 * wy1 * ((vx1 && vy1) ? 1.0f : 0.0f);

    const float msum = a00 + a10 + a01 + a11;
    const float mask = (msum >= 0.9999f) ? 1.0f : 0.0f;
    w00[k] = a00 * mask; w10[k] = a10 * mask;
    w01[k] = a01 * mask; w11[k] = a11 * mask;

    const int ix0 = min(max((int)x0f, 0), W - 1);
    const int ix1 = min(max((int)x1f, 0), W - 1);
    const int iy0 = min(max((int)y0f, 0), H - 1);
    const int iy1 = min(max((int)y1f, 0), H - 1);

    const int l0x = ix0 - (c0 - HALO);
    const int l1x = ix1 - (c0 - HALO);
    const int l0y = iy0 - (r0 - HALO);
    const int l1y = iy1 - (r0 - HALO);
    const bool intile = (l0x >= 0) & (l1x < SW) & (l0y >= 0) & (l1y < SH);

    if (intile) {
      o00[k] = l0y * SW + l0x; o10[k] = l0y * SW + l1x;
      o01[k] = l1y * SW + l0x; o11[k] = l1y * SW + l1x;
    } else {
      o00[k] = iy0 * W + ix0; o10[k] = iy0 * W + ix1;
      o01[k] = iy1 * W + ix0; o11[k] = iy1 * W + ix1;
      fb |= (1u << k);
    }
    pout[k] = h * W + w;
  }

  // ---- channel loop: stage tile -> sample from LDS ----
  for (int c = cg0; c < cg0 + CPG; ++c) {
    const float* __restrict__ xp = x + ((size_t)b * C + c) * HW;
    float* __restrict__ op = out + ((size_t)b * C + c) * HW;

#pragma unroll
    for (int i = 0; i < 11; ++i) {
      const int s = t + 256 * i;
      if (s < SN) {
        const int vr = s / SW;
        const int vc = s - vr * SW;
        const int grow = min(max(r0 - HALO + vr, 0), H - 1);
        const int gcol = min(max(c0 - HALO + vc, 0), W - 1);
        sm[s] = xp[grow * W + gcol];
      }
    }
    __syncthreads();

#pragma unroll
    for (int k = 0; k < 4; ++k) {
      float v00, v10, v01, v11;
      if (!((fb >> k) & 1u)) {
        v00 = sm[o00[k]]; v10 = sm[o10[k]];
        v01 = sm[o01[k]]; v11 = sm[o11[k]];
      } else {  // rare: displacement beyond halo -> global gather
        v00 = xp[o00[k]]; v10 = xp[o10[k]];
        v01 = xp[o01[k]]; v11 = xp[o11[k]];
      }
      const float r = w00[k] * v00 + w10[k] * v10 + w01[k] * v01 + w11[k] * v11;
      __builtin_nontemporal_store(r, &op[pout[k]]);
    }
    __syncthreads();
  }
}

extern "C" void kernel_launch(void* const* d_in, const int* in_sizes, int n_in,
                              void* d_out, int out_size, void* d_ws, size_t ws_size,
                              hipStream_t stream) {
  const float* x = (const float*)d_in[0];
  const float* flow = (const float*)d_in[1];
  float* out = (float*)d_out;
  dim3 grid((H / TH) * (W / TW) * B, C / CPG);  // (512, 4)
  warp_flow_kernel<<<grid, dim3(256), 0, stream>>>(x, flow, out);
}